// Round 12
// baseline (149.927 us; speedup 1.0000x reference)
//
#include <hip/hip_runtime.h>

// ---------------------------------------------------------------------------
// MultiHeadSelfAttentionWithRoPE  (B=2, S=2048, D=1024, H=16, d=64, causal)
// cvt(fp32->bf16) -> QKV gemm (DMA staging; RoPE fused in epilogue; V written
// transposed+permuted) -> flash attn (1-wave blocks, K/V read DIRECT from
// L2-resident global into register fragments, no LDS/barriers) -> O gemm
// ---------------------------------------------------------------------------

typedef unsigned short u16;
typedef unsigned int   u32;
typedef u16    ushort8 __attribute__((ext_vector_type(8)));
typedef u16    u16x4   __attribute__((ext_vector_type(4)));
typedef short  s16x4   __attribute__((ext_vector_type(4)));
typedef short  s16x8   __attribute__((ext_vector_type(8)));
typedef __bf16 bf16x8  __attribute__((ext_vector_type(8)));
typedef float  f32x4   __attribute__((ext_vector_type(4)));

#define D_MODEL 1024
#define SEQ     2048
#define NHEAD   16
#define HDIM    64
#define SEG     1048576

__device__ __forceinline__ u16 f2bf(float f) {        // RNE fp32->bf16
    u32 u = __builtin_bit_cast(u32, f);
    u32 r = (u + 0x7FFFu + ((u >> 16) & 1u)) >> 16;
    return (u16)r;
}
__device__ __forceinline__ bf16x8 as_bf(ushort8 v) {
    return __builtin_bit_cast(bf16x8, v);
}
__device__ __forceinline__ f32x4 mfma16(bf16x8 a, bf16x8 b, f32x4 c) {
    return __builtin_amdgcn_mfma_f32_16x16x32_bf16(a, b, c, 0, 0, 0);
}
// async global->LDS DMA: 16B per lane, dest = wave-uniform base + lane*16
__device__ __forceinline__ void dma16(const u16* g, u16* l) {
    __builtin_amdgcn_global_load_lds(
        (const __attribute__((address_space(1))) void*)g,
        (__attribute__((address_space(3))) void*)l, 16, 0, 0);
}

// ---------------------------------------------------------------------------
// fp32 -> bf16 conversion: z<4 quarters of x, z=4..7 -> W_Q,W_K,W_V,W_O
// ---------------------------------------------------------------------------
__global__ __launch_bounds__(256) void k_cvt(
    const float* __restrict__ x,  const float* __restrict__ wq,
    const float* __restrict__ wk, const float* __restrict__ wv,
    const float* __restrict__ wo, u16* __restrict__ dst0)
{
    const int z = blockIdx.z;
    const float* src; u16* dst;
    if      (z < 4)  { src = x + (size_t)z * SEG; dst = dst0 + (size_t)z * SEG; }
    else if (z == 4) { src = wq; dst = dst0 + (size_t)4 * SEG; }
    else if (z == 5) { src = wk; dst = dst0 + (size_t)5 * SEG; }
    else if (z == 6) { src = wv; dst = dst0 + (size_t)6 * SEG; }
    else             { src = wo; dst = dst0 + (size_t)7 * SEG; }
    const size_t i = ((size_t)blockIdx.x * 256 + threadIdx.x) * 8;
    f32x4 f0 = *(const f32x4*)(src + i);
    f32x4 f1 = *(const f32x4*)(src + i + 4);
    ushort8 o;
    o[0]=f2bf(f0[0]); o[1]=f2bf(f0[1]); o[2]=f2bf(f0[2]); o[3]=f2bf(f0[3]);
    o[4]=f2bf(f1[0]); o[5]=f2bf(f1[1]); o[6]=f2bf(f1[2]); o[7]=f2bf(f1[3]);
    *(ushort8*)(dst + i) = o;
}

// ---------------------------------------------------------------------------
// NT GEMM: C[M,N] = A[M,K]*W[N,K]^T, K=1024, 128x128 tile, BK=32, 4 waves,
// global_load_lds DMA staging, double-buffered, 1 barrier/K-step.
// LS (32KB) passed in by the kernel; reused as epilogue transpose buffer.
// MODE 0: fp32 out [token][D_MODEL]                 (O projection)
// MODE 1: bf16 out [b,h,s,d], RoPE + 0.125*log2e    (Q)
// MODE 2: bf16 out [b,h,s,d], RoPE                  (K)
// MODE 3: bf16 out [b,h,d,s], paired-nt k-perm      (V^T)
// ---------------------------------------------------------------------------
template<int MODE>
__device__ __forceinline__ void gemm_body(
    u16* __restrict__ LS,
    const u16* __restrict__ A, const u16* __restrict__ W,
    u16* __restrict__ outB, float* __restrict__ outF,
    const int* __restrict__ pos, int bm, int bn)
{
    u16* Als = LS;           // [2][4096] u16
    u16* Bls = LS + 8192;    // [2][4096] u16
    const int tid  = threadIdx.x;
    const int lane = tid & 63;
    const int wv   = tid >> 6;
    const int wm   = wv >> 1, wn = wv & 1;
    const int l15  = lane & 15, l4 = lane >> 4;

    // DMA source offsets (slot s holds global chunk (s&3)^(r&3) of row r=s>>2)
    const int s0 = tid, s1 = 256 + tid;
    const int r0 = s0 >> 2, p0 = (s0 & 3) ^ (r0 & 3);
    const int r1 = s1 >> 2, p1 = (s1 & 3) ^ (r1 & 3);
    const u16* gA0 = A + (size_t)(bm + r0) * D_MODEL + p0 * 8;
    const u16* gA1 = A + (size_t)(bm + r1) * D_MODEL + p1 * 8;
    const u16* gB0 = W + (size_t)(bn + r0) * D_MODEL + p0 * 8;
    const u16* gB1 = W + (size_t)(bn + r1) * D_MODEL + p1 * 8;
    const int lb0 = wv * 512, lb1 = 2048 + wv * 512;   // wave-uniform LDS bases

    const f32x4 zz = {0.f, 0.f, 0.f, 0.f};
    f32x4 acc[4][4];
#pragma unroll
    for (int i = 0; i < 4; i++)
#pragma unroll
        for (int j = 0; j < 4; j++) acc[i][j] = zz;

    dma16(gA0, Als + lb0);
    dma16(gA1, Als + lb1);
    dma16(gB0, Bls + lb0);
    dma16(gB1, Bls + lb1);
    __syncthreads();

    for (int t = 0; t < 32; ++t) {
        const int cur = t & 1;
        if (t < 31) {
            const int ko = (t + 1) * 32;
            const int nb = (cur ^ 1) * 4096;
            dma16(gA0 + ko, Als + nb + lb0);
            dma16(gA1 + ko, Als + nb + lb1);
            dma16(gB0 + ko, Bls + nb + lb0);
            dma16(gB1 + ko, Bls + nb + lb1);
        }
        bf16x8 af[4], bfr[4];
#pragma unroll
        for (int mi = 0; mi < 4; mi++) {
            const int row = wm * 64 + mi * 16 + l15;
            af[mi] = as_bf(*(const ushort8*)((const char*)(Als + cur * 4096) +
                         row * 64 + ((l4 * 16) ^ ((row & 3) << 4))));
        }
#pragma unroll
        for (int ni = 0; ni < 4; ni++) {
            const int row = wn * 64 + ni * 16 + l15;
            bfr[ni] = as_bf(*(const ushort8*)((const char*)(Bls + cur * 4096) +
                          row * 64 + ((l4 * 16) ^ ((row & 3) << 4))));
        }
#pragma unroll
        for (int mi = 0; mi < 4; mi++)
#pragma unroll
            for (int ni = 0; ni < 4; ni++)
                acc[mi][ni] = mfma16(af[mi], bfr[ni], acc[mi][ni]);
        __syncthreads();   // drains DMA (vmcnt) + LDS reads (lgkmcnt)
    }

    // ------------------------- epilogue -------------------------
    if constexpr (MODE == 0) {
#pragma unroll
        for (int mi = 0; mi < 4; mi++)
#pragma unroll
            for (int ni = 0; ni < 4; ni++) {
                const int rowb = bm + wm * 64 + mi * 16 + l4 * 4;
                const int colg = bn + wn * 64 + ni * 16 + l15;
#pragma unroll
                for (int r = 0; r < 4; r++)
                    outF[(size_t)(rowb + r) * D_MODEL + colg] = acc[mi][ni][r];
            }
        return;
    }

    // per-wave private 8KB transpose region (K-loop's final barrier passed)
    u16* Sreg = LS + wv * 4096;
    const int bq    = (bm + wm * 64) >> 11;        // batch
    const int hq    = (bn + wn * 64) >> 6;         // head
    const int srow0 = (bm + wm * 64) & 2047;       // token block base

    if constexpr (MODE == 1 || MODE == 2) {
        // RoPE: pair elems are adjacent lanes (d = ni*16+l15, parity = l15&1)
        const float lscale = (MODE == 1) ? 0.125f * 1.44269504088896340736f : 1.0f;
        const float sgn    = (l15 & 1) ? 1.0f : -1.0f;   // vo*sn sign
        float invf[4];
#pragma unroll
        for (int ni = 0; ni < 4; ni++)
            invf[ni] = exp2f(-(float)(ni * 8 + (l15 >> 1)) * 0.41524101186092435f);
#pragma unroll
        for (int mi = 0; mi < 4; mi++)
#pragma unroll
            for (int r = 0; r < 4; r++) {
                const int sl = mi * 16 + l4 * 4 + r;              // s_local
                const float pv = (float)pos[(srow0 + sl) & 2047];
#pragma unroll
                for (int ni = 0; ni < 4; ni++) {
                    const float v  = acc[mi][ni][r];
                    const float vo = __shfl_xor(v, 1);
                    float sn, cs;
                    __sincosf(pv * invf[ni], &sn, &cs);
                    const float out = (v * cs + vo * sn * sgn) * lscale;
                    const int colb = (ni * 32 + l15 * 2) ^ ((sl & 7) << 4);
                    *(u16*)((char*)Sreg + sl * 128 + colb) = f2bf(out);
                }
            }
        asm volatile("s_waitcnt lgkmcnt(0)" ::: "memory");
        __builtin_amdgcn_sched_barrier(0);
        // read back rows of s (128B of d), store coalesced [b,h,s,d]
#pragma unroll
        for (int i = 0; i < 8; i++) {
            const int sl = (lane >> 3) + i * 8;
            const int cb = ((lane & 7) * 16) ^ ((sl & 7) << 4);
            ushort8 vv = *(const ushort8*)((char*)Sreg + sl * 128 + cb);
            *(ushort8*)(outB + ((size_t)(bq * NHEAD + hq) * SEQ + srow0 + sl) * HDIM
                        + (lane & 7) * 8) = vv;
        }
    } else {  // MODE == 3: V^T with paired-nt k-permutation
#pragma unroll
        for (int mi = 0; mi < 4; mi++) {
            const int s6 = mi * 16 + l4 * 4;   // s_local base (r adds 0..3)
            const int pp = ((s6 >> 5) & 1) * 32 + ((s6 >> 2) & 3) * 8 +
                           ((s6 >> 4) & 1) * 4;
#pragma unroll
            for (int ni = 0; ni < 4; ni++) {
                const int dl = ni * 16 + l15;   // d_local row
                u16x4 o;
#pragma unroll
                for (int r = 0; r < 4; r++) o[r] = f2bf(acc[mi][ni][r]);
                const int colb = (pp * 2) ^ ((dl & 7) << 4);
                *(u16x4*)((char*)Sreg + dl * 128 + colb) = o;
            }
        }
        asm volatile("s_waitcnt lgkmcnt(0)" ::: "memory");
        __builtin_amdgcn_sched_barrier(0);
        // read back rows of d (128B of perm(s)), store [b,h,d,s]
#pragma unroll
        for (int i = 0; i < 8; i++) {
            const int dl = (lane >> 3) + i * 8;
            const int cb = ((lane & 7) * 16) ^ ((dl & 7) << 4);
            ushort8 vv = *(const ushort8*)((char*)Sreg + dl * 128 + cb);
            *(ushort8*)(outB + ((size_t)(bq * NHEAD + hq) * HDIM + dl) * SEQ
                        + srow0 + (lane & 7) * 8) = vv;
        }
    }
}

__global__ __launch_bounds__(256) void k_gemm_qkv(
    const u16* __restrict__ xb,
    const u16* __restrict__ wq, const u16* __restrict__ wk, const u16* __restrict__ wv,
    u16* __restrict__ Qb, u16* __restrict__ Kb, u16* __restrict__ Vtb,
    const int* __restrict__ pos)
{
    __shared__ u16 LS[16384];   // single 32KB allocation for all instantiations
    const int z = blockIdx.z;
    if      (z == 0) gemm_body<1>(LS, xb, wq, Qb,  nullptr, pos, blockIdx.y*128, blockIdx.x*128);
    else if (z == 1) gemm_body<2>(LS, xb, wk, Kb,  nullptr, pos, blockIdx.y*128, blockIdx.x*128);
    else             gemm_body<3>(LS, xb, wv, Vtb, nullptr, pos, blockIdx.y*128, blockIdx.x*128);
}

__global__ __launch_bounds__(256) void k_gemm_o(
    const u16* __restrict__ yb, const u16* __restrict__ wo, float* __restrict__ out)
{
    __shared__ u16 LS[16384];
    gemm_body<0>(LS, yb, wo, nullptr, out, nullptr, blockIdx.y*128, blockIdx.x*128);
}

// ---------------------------------------------------------------------------
// Causal flash attention, NO LDS / NO barriers: 1 wave per block, 32 q-rows
// (2 mt sub-tiles). K and V^T fragments are loaded DIRECTLY from global into
// registers each 64-key step -- K/V for a head (512KB) is L2-resident, and
// all blocks of one bh land on one XCD (flat id % 8 == bh % 8). Fragment
// loads cover full 128B lines pairwise (ks / nt2 halves) -> ~100% line use.
//   St = mfma(A=K-rows, B=Q-rows) -> lane holds P[k=l4*4+r][q=l15]
//   = B-frag of mfma_16x16x16bf16_1k. PV: O^T = mfma(A=V^T-frag, B=P).
// 2048 blocks, longest-first; waves fully independent (no lockstep).
// ---------------------------------------------------------------------------
__global__ __launch_bounds__(64, 3) void k_attn(
    const u16* __restrict__ Qb, const u16* __restrict__ Kb,
    const u16* __restrict__ Vtb, u16* __restrict__ Yb)
{
    const int lane = threadIdx.x;            // 0..63, one wave
    const int l15  = lane & 15, l4 = lane >> 4;
    const int bh   = blockIdx.x;             // b*16+h
    const int qs   = 63 - blockIdx.y;        // 32-q slot, longest first
    const int qw   = qs * 32;                // wave's first query
    const size_t base = (size_t)bh * SEQ * HDIM;
    const u16* Qg = Qb  + base;
    const u16* Kg = Kb  + base;
    const u16* Vg = Vtb + base;              // [d][s] layout, 64-block k-perm

    // Q B-frags (RoPE + scale already applied): B[n=q=l15][kk=d=l4*8+i]
    bf16x8 qf[2][2];
#pragma unroll
    for (int mt = 0; mt < 2; mt++)
#pragma unroll
        for (int ks = 0; ks < 2; ks++)
            qf[mt][ks] = as_bf(*(const ushort8*)(
                Qg + (size_t)(qw + mt * 16 + l15) * HDIM + ks * 32 + l4 * 8));

    const f32x4 zz = {0.f, 0.f, 0.f, 0.f};
    f32x4 acc[2][4];              // O^T: lane holds [d=nd*16+l4*4+r][q=l15]
    float mst[2] = {-1e30f, -1e30f}, lst[2] = {0.f, 0.f};
#pragma unroll
    for (int mt = 0; mt < 2; mt++)
#pragma unroll
        for (int n = 0; n < 4; n++) acc[mt][n] = zz;

    // per-lane loop-invariant offsets (u16 elems)
    const int kofs = l15 * HDIM + l4 * 8;    // K: row l15 (+nt*16), col half ks
    const int vofs = l15 * SEQ  + l4 * 8;    // V^T: row l15 (+nd*16), col (+nt2*32)

    const int nkb = (qs >> 1) + 1;

    for (int kb = 0; kb < nkb; ++kb) {
        const int kbb = kb * 64;

        // --- K fragments direct from global (L2-hit) ---
        bf16x8 kf[4][2];
#pragma unroll
        for (int nt = 0; nt < 4; nt++) {
            const u16* kr = Kg + (size_t)(kbb + nt * 16) * HDIM + kofs;
            kf[nt][0] = as_bf(*(const ushort8*)(kr));
            kf[nt][1] = as_bf(*(const ushort8*)(kr + 32));
        }
        // --- V^T fragments direct from global (independent of K) ---
        s16x8 vw[2][4];
#pragma unroll
        for (int nt2 = 0; nt2 < 2; nt2++)
#pragma unroll
            for (int nd = 0; nd < 4; nd++)
                vw[nt2][nd] = *(const s16x8*)(Vg + (size_t)(nd * 16) * SEQ +
                                              kbb + nt2 * 32 + vofs);

        // --- S^T = K·Q^T : lane holds S[k=kbb+nt*16+l4*4+r][q=qw+mt*16+l15] ---
        f32x4 st[2][4];
        __builtin_amdgcn_s_setprio(1);
#pragma unroll
        for (int mt = 0; mt < 2; mt++)
#pragma unroll
            for (int nt = 0; nt < 4; nt++) {
                f32x4 sv   = mfma16(kf[nt][0], qf[mt][0], zz);
                st[mt][nt] = mfma16(kf[nt][1], qf[mt][1], sv);
            }
        __builtin_amdgcn_s_setprio(0);

        // --- softmax per mt; mask only on the last (diagonal) step ---
        s16x4 pb[2][4];
#pragma unroll
        for (int mt = 0; mt < 2; mt++) {
            if (kb == nkb - 1) {
                const int qg = qw + mt * 16 + l15;
#pragma unroll
                for (int nt = 0; nt < 4; nt++)
#pragma unroll
                    for (int r = 0; r < 4; r++) {
                        const int kg = kbb + nt * 16 + l4 * 4 + r;
                        st[mt][nt][r] = (kg <= qg) ? st[mt][nt][r] : -1e30f;
                    }
            }
            float m0 = fmaxf(fmaxf(st[mt][0][0], st[mt][0][1]),
                             fmaxf(st[mt][0][2], st[mt][0][3]));
            float m1 = fmaxf(fmaxf(st[mt][1][0], st[mt][1][1]),
                             fmaxf(st[mt][1][2], st[mt][1][3]));
            float m2 = fmaxf(fmaxf(st[mt][2][0], st[mt][2][1]),
                             fmaxf(st[mt][2][2], st[mt][2][3]));
            float m3 = fmaxf(fmaxf(st[mt][3][0], st[mt][3][1]),
                             fmaxf(st[mt][3][2], st[mt][3][3]));
            float m  = fmaxf(fmaxf(m0, m1), fmaxf(m2, m3));
            m = fmaxf(m, __shfl_xor(m, 16));
            m = fmaxf(m, __shfl_xor(m, 32));
            if (!__all(m - mst[mt] <= 8.0f)) {    // defer-max (T13, base-2)
                const float mn = fmaxf(mst[mt], m);
                const float sf = exp2f(mst[mt] - mn);
                mst[mt] = mn;
                lst[mt] *= sf;
#pragma unroll
                for (int nd = 0; nd < 4; nd++) acc[mt][nd] *= sf;
            }
            const float mm = mst[mt];
            float pg[4];
#pragma unroll
            for (int nt = 0; nt < 4; nt++) {
                float p0 = exp2f(st[mt][nt][0] - mm), p1 = exp2f(st[mt][nt][1] - mm);
                float p2 = exp2f(st[mt][nt][2] - mm), p3 = exp2f(st[mt][nt][3] - mm);
                pg[nt] = (p0 + p1) + (p2 + p3);
                s16x4 pv;
                pv[0] = (short)__builtin_bit_cast(u16, (__bf16)p0);
                pv[1] = (short)__builtin_bit_cast(u16, (__bf16)p1);
                pv[2] = (short)__builtin_bit_cast(u16, (__bf16)p2);
                pv[3] = (short)__builtin_bit_cast(u16, (__bf16)p3);
                pb[mt][nt] = pv;
            }
            float ps = (pg[0] + pg[1]) + (pg[2] + pg[3]);
            ps += __shfl_xor(ps, 16);
            ps += __shfl_xor(ps, 32);
            lst[mt] += ps;
        }

        // --- O^T += V^T·P : vlo/vhi are register halves (no VALU) ---
        __builtin_amdgcn_s_setprio(1);
#pragma unroll
        for (int nt2 = 0; nt2 < 2; nt2++)
#pragma unroll
            for (int nd = 0; nd < 4; nd++) {
                const s16x4 vlo = __builtin_shufflevector(vw[nt2][nd], vw[nt2][nd],
                                                          0, 1, 2, 3);
                const s16x4 vhi = __builtin_shufflevector(vw[nt2][nd], vw[nt2][nd],
                                                          4, 5, 6, 7);
#pragma unroll
                for (int mt = 0; mt < 2; mt++) {
                    acc[mt][nd] = __builtin_amdgcn_mfma_f32_16x16x16bf16_1k(
                        vlo, pb[mt][2 * nt2], acc[mt][nd], 0, 0, 0);
                    acc[mt][nd] = __builtin_amdgcn_mfma_f32_16x16x16bf16_1k(
                        vhi, pb[mt][2 * nt2 + 1], acc[mt][nd], 0, 0, 0);
                }
            }
        __builtin_amdgcn_s_setprio(0);
    }

    // --- epilogue: lane holds O^T[d=nd*16+l4*4+r][q=l15]; write /lst ---
    const int b = bh >> 4, h = bh & 15;
#pragma unroll
    for (int mt = 0; mt < 2; mt++) {
        const float inv = 1.0f / lst[mt];
        const int q = qw + mt * 16 + l15;
#pragma unroll
        for (int nd = 0; nd < 4; nd++) {
            u16x4 o;
#pragma unroll
            for (int r = 0; r < 4; r++)
                o[r] = __builtin_bit_cast(u16, (__bf16)(acc[mt][nd][r] * inv));
            const int d = nd * 16 + l4 * 4;
            *(u16x4*)(Yb + (size_t)(b * SEQ + q) * D_MODEL + h * HDIM + d) = o;
        }
    }
}

// ---------------------------------------------------------------------------
extern "C" void kernel_launch(void* const* d_in, const int* in_sizes, int n_in,
                              void* d_out, int out_size, void* d_ws, size_t ws_size,
                              hipStream_t stream)
{
    const float* x  = (const float*)d_in[0];
    const float* wq = (const float*)d_in[1];
    const float* wk = (const float*)d_in[2];
    const float* wv = (const float*)d_in[3];
    const float* wo = (const float*)d_in[4];
    const int*  pos = (const int*)d_in[5];
    float* out = (float*)d_out;

    // workspace (bf16): [x 4M | wq 1M | wk 1M | wv 1M | wo 1M | Q 4M | K 4M | Vt 4M]
    // y (attention output) aliases x (x is dead after the QKV GEMM).
    if (ws_size < (size_t)41943040) return;
    u16* xb  = (u16*)d_ws;
    u16* wqb = xb  + (size_t)4 * SEG;
    u16* wkb = wqb + SEG;
    u16* wvb = wkb + SEG;
    u16* wob = wvb + SEG;
    u16* Qb  = wob + SEG;
    u16* Kb  = Qb  + (size_t)4 * SEG;
    u16* Vtb = Kb  + (size_t)4 * SEG;   // [b,h,d,s], k-permuted per 64-block
    u16* Yb  = xb;

    k_cvt     <<<dim3(512, 1, 8), 256, 0, stream>>>(x, wq, wk, wv, wo, xb);
    k_gemm_qkv<<<dim3(8, 32, 3),  256, 0, stream>>>(xb, wqb, wkb, wvb, Qb, Kb, Vtb, pos);
    k_attn    <<<dim3(32, 64),    64,  0, stream>>>(Qb, Kb, Vtb, Yb);
    k_gemm_o  <<<dim3(8, 32),     256, 0, stream>>>(Yb, wob, out);
}

// Round 14
// 119.039 us; speedup vs baseline: 1.2595x; 1.2595x over previous
//
#include <hip/hip_runtime.h>

// ---------------------------------------------------------------------------
// MultiHeadSelfAttentionWithRoPE  (B=2, S=2048, D=1024, H=16, d=64, causal)
// cvt(fp32->bf16) -> QKV gemm (DMA staging; RoPE fused in epilogue; V written
// transposed+permuted) -> flash attn (QBLK=64, deferred-PV, deferred l-sum,
// DMA-staged K/V^T) -> O gemm
// ---------------------------------------------------------------------------

typedef unsigned short u16;
typedef unsigned int   u32;
typedef u16    ushort8 __attribute__((ext_vector_type(8)));
typedef u16    u16x4   __attribute__((ext_vector_type(4)));
typedef short  s16x4   __attribute__((ext_vector_type(4)));
typedef short  s16x8   __attribute__((ext_vector_type(8)));
typedef __bf16 bf16x8  __attribute__((ext_vector_type(8)));
typedef float  f32x4   __attribute__((ext_vector_type(4)));

#define D_MODEL 1024
#define SEQ     2048
#define NHEAD   16
#define HDIM    64
#define SEG     1048576

__device__ __forceinline__ u16 f2bf(float f) {        // RNE fp32->bf16
    u32 u = __builtin_bit_cast(u32, f);
    u32 r = (u + 0x7FFFu + ((u >> 16) & 1u)) >> 16;
    return (u16)r;
}
__device__ __forceinline__ bf16x8 as_bf(ushort8 v) {
    return __builtin_bit_cast(bf16x8, v);
}
__device__ __forceinline__ f32x4 mfma16(bf16x8 a, bf16x8 b, f32x4 c) {
    return __builtin_amdgcn_mfma_f32_16x16x32_bf16(a, b, c, 0, 0, 0);
}
// async global->LDS DMA: 16B per lane, dest = wave-uniform base + lane*16
__device__ __forceinline__ void dma16(const u16* g, u16* l) {
    __builtin_amdgcn_global_load_lds(
        (const __attribute__((address_space(1))) void*)g,
        (__attribute__((address_space(3))) void*)l, 16, 0, 0);
}

// ---------------------------------------------------------------------------
// fp32 -> bf16 conversion: z<4 quarters of x, z=4..7 -> W_Q,W_K,W_V,W_O
// ---------------------------------------------------------------------------
__global__ __launch_bounds__(256) void k_cvt(
    const float* __restrict__ x,  const float* __restrict__ wq,
    const float* __restrict__ wk, const float* __restrict__ wv,
    const float* __restrict__ wo, u16* __restrict__ dst0)
{
    const int z = blockIdx.z;
    const float* src; u16* dst;
    if      (z < 4)  { src = x + (size_t)z * SEG; dst = dst0 + (size_t)z * SEG; }
    else if (z == 4) { src = wq; dst = dst0 + (size_t)4 * SEG; }
    else if (z == 5) { src = wk; dst = dst0 + (size_t)5 * SEG; }
    else if (z == 6) { src = wv; dst = dst0 + (size_t)6 * SEG; }
    else             { src = wo; dst = dst0 + (size_t)7 * SEG; }
    const size_t i = ((size_t)blockIdx.x * 256 + threadIdx.x) * 8;
    f32x4 f0 = *(const f32x4*)(src + i);
    f32x4 f1 = *(const f32x4*)(src + i + 4);
    ushort8 o;
    o[0]=f2bf(f0[0]); o[1]=f2bf(f0[1]); o[2]=f2bf(f0[2]); o[3]=f2bf(f0[3]);
    o[4]=f2bf(f1[0]); o[5]=f2bf(f1[1]); o[6]=f2bf(f1[2]); o[7]=f2bf(f1[3]);
    *(ushort8*)(dst + i) = o;
}

// ---------------------------------------------------------------------------
// NT GEMM: C[M,N] = A[M,K]*W[N,K]^T, K=1024, 128x128 tile, BK=32, 4 waves,
// global_load_lds DMA staging, double-buffered, 1 barrier/K-step.
// LS (32KB) passed in by the kernel; reused as epilogue transpose buffer.
// MODE 0: fp32 out [token][D_MODEL]                 (O projection)
// MODE 1: bf16 out [b,h,s,d], RoPE + 0.125*log2e    (Q)
// MODE 2: bf16 out [b,h,s,d], RoPE                  (K)
// MODE 3: bf16 out [b,h,d,s], paired-nt k-perm      (V^T)
// ---------------------------------------------------------------------------
template<int MODE>
__device__ __forceinline__ void gemm_body(
    u16* __restrict__ LS,
    const u16* __restrict__ A, const u16* __restrict__ W,
    u16* __restrict__ outB, float* __restrict__ outF,
    const int* __restrict__ pos, int bm, int bn)
{
    u16* Als = LS;           // [2][4096] u16
    u16* Bls = LS + 8192;    // [2][4096] u16
    const int tid  = threadIdx.x;
    const int lane = tid & 63;
    const int wv   = tid >> 6;
    const int wm   = wv >> 1, wn = wv & 1;
    const int l15  = lane & 15, l4 = lane >> 4;

    // DMA source offsets (slot s holds global chunk (s&3)^(r&3) of row r=s>>2)
    const int s0 = tid, s1 = 256 + tid;
    const int r0 = s0 >> 2, p0 = (s0 & 3) ^ (r0 & 3);
    const int r1 = s1 >> 2, p1 = (s1 & 3) ^ (r1 & 3);
    const u16* gA0 = A + (size_t)(bm + r0) * D_MODEL + p0 * 8;
    const u16* gA1 = A + (size_t)(bm + r1) * D_MODEL + p1 * 8;
    const u16* gB0 = W + (size_t)(bn + r0) * D_MODEL + p0 * 8;
    const u16* gB1 = W + (size_t)(bn + r1) * D_MODEL + p1 * 8;
    const int lb0 = wv * 512, lb1 = 2048 + wv * 512;   // wave-uniform LDS bases

    const f32x4 zz = {0.f, 0.f, 0.f, 0.f};
    f32x4 acc[4][4];
#pragma unroll
    for (int i = 0; i < 4; i++)
#pragma unroll
        for (int j = 0; j < 4; j++) acc[i][j] = zz;

    dma16(gA0, Als + lb0);
    dma16(gA1, Als + lb1);
    dma16(gB0, Bls + lb0);
    dma16(gB1, Bls + lb1);
    __syncthreads();

    for (int t = 0; t < 32; ++t) {
        const int cur = t & 1;
        if (t < 31) {
            const int ko = (t + 1) * 32;
            const int nb = (cur ^ 1) * 4096;
            dma16(gA0 + ko, Als + nb + lb0);
            dma16(gA1 + ko, Als + nb + lb1);
            dma16(gB0 + ko, Bls + nb + lb0);
            dma16(gB1 + ko, Bls + nb + lb1);
        }
        bf16x8 af[4], bfr[4];
#pragma unroll
        for (int mi = 0; mi < 4; mi++) {
            const int row = wm * 64 + mi * 16 + l15;
            af[mi] = as_bf(*(const ushort8*)((const char*)(Als + cur * 4096) +
                         row * 64 + ((l4 * 16) ^ ((row & 3) << 4))));
        }
#pragma unroll
        for (int ni = 0; ni < 4; ni++) {
            const int row = wn * 64 + ni * 16 + l15;
            bfr[ni] = as_bf(*(const ushort8*)((const char*)(Bls + cur * 4096) +
                          row * 64 + ((l4 * 16) ^ ((row & 3) << 4))));
        }
#pragma unroll
        for (int mi = 0; mi < 4; mi++)
#pragma unroll
            for (int ni = 0; ni < 4; ni++)
                acc[mi][ni] = mfma16(af[mi], bfr[ni], acc[mi][ni]);
        __syncthreads();   // drains DMA (vmcnt) + LDS reads (lgkmcnt)
    }

    // ------------------------- epilogue -------------------------
    if constexpr (MODE == 0) {
#pragma unroll
        for (int mi = 0; mi < 4; mi++)
#pragma unroll
            for (int ni = 0; ni < 4; ni++) {
                const int rowb = bm + wm * 64 + mi * 16 + l4 * 4;
                const int colg = bn + wn * 64 + ni * 16 + l15;
#pragma unroll
                for (int r = 0; r < 4; r++)
                    outF[(size_t)(rowb + r) * D_MODEL + colg] = acc[mi][ni][r];
            }
        return;
    }

    // per-wave private 8KB transpose region (K-loop's final barrier passed)
    u16* Sreg = LS + wv * 4096;
    const int bq    = (bm + wm * 64) >> 11;        // batch
    const int hq    = (bn + wn * 64) >> 6;         // head
    const int srow0 = (bm + wm * 64) & 2047;       // token block base

    if constexpr (MODE == 1 || MODE == 2) {
        // RoPE: pair elems are adjacent lanes (d = ni*16+l15, parity = l15&1)
        const float lscale = (MODE == 1) ? 0.125f * 1.44269504088896340736f : 1.0f;
        const float sgn    = (l15 & 1) ? 1.0f : -1.0f;   // vo*sn sign
        float invf[4];
#pragma unroll
        for (int ni = 0; ni < 4; ni++)
            invf[ni] = exp2f(-(float)(ni * 8 + (l15 >> 1)) * 0.41524101186092435f);
#pragma unroll
        for (int mi = 0; mi < 4; mi++)
#pragma unroll
            for (int r = 0; r < 4; r++) {
                const int sl = mi * 16 + l4 * 4 + r;              // s_local
                const float pv = (float)pos[(srow0 + sl) & 2047];
#pragma unroll
                for (int ni = 0; ni < 4; ni++) {
                    const float v  = acc[mi][ni][r];
                    const float vo = __shfl_xor(v, 1);
                    float sn, cs;
                    __sincosf(pv * invf[ni], &sn, &cs);
                    const float out = (v * cs + vo * sn * sgn) * lscale;
                    const int colb = (ni * 32 + l15 * 2) ^ ((sl & 7) << 4);
                    *(u16*)((char*)Sreg + sl * 128 + colb) = f2bf(out);
                }
            }
        asm volatile("s_waitcnt lgkmcnt(0)" ::: "memory");
        __builtin_amdgcn_sched_barrier(0);
        // read back rows of s (128B of d), store coalesced [b,h,s,d]
#pragma unroll
        for (int i = 0; i < 8; i++) {
            const int sl = (lane >> 3) + i * 8;
            const int cb = ((lane & 7) * 16) ^ ((sl & 7) << 4);
            ushort8 vv = *(const ushort8*)((char*)Sreg + sl * 128 + cb);
            *(ushort8*)(outB + ((size_t)(bq * NHEAD + hq) * SEQ + srow0 + sl) * HDIM
                        + (lane & 7) * 8) = vv;
        }
    } else {  // MODE == 3: V^T with paired-nt k-permutation
#pragma unroll
        for (int mi = 0; mi < 4; mi++) {
            const int s6 = mi * 16 + l4 * 4;   // s_local base (r adds 0..3)
            const int pp = ((s6 >> 5) & 1) * 32 + ((s6 >> 2) & 3) * 8 +
                           ((s6 >> 4) & 1) * 4;
#pragma unroll
            for (int ni = 0; ni < 4; ni++) {
                const int dl = ni * 16 + l15;   // d_local row
                u16x4 o;
#pragma unroll
                for (int r = 0; r < 4; r++) o[r] = f2bf(acc[mi][ni][r]);
                const int colb = (pp * 2) ^ ((dl & 7) << 4);
                *(u16x4*)((char*)Sreg + dl * 128 + colb) = o;
            }
        }
        asm volatile("s_waitcnt lgkmcnt(0)" ::: "memory");
        __builtin_amdgcn_sched_barrier(0);
        // read back rows of d (128B of perm(s)), store [b,h,d,s]
#pragma unroll
        for (int i = 0; i < 8; i++) {
            const int dl = (lane >> 3) + i * 8;
            const int cb = ((lane & 7) * 16) ^ ((dl & 7) << 4);
            ushort8 vv = *(const ushort8*)((char*)Sreg + dl * 128 + cb);
            *(ushort8*)(outB + ((size_t)(bq * NHEAD + hq) * HDIM + dl) * SEQ
                        + srow0 + (lane & 7) * 8) = vv;
        }
    }
}

__global__ __launch_bounds__(256) void k_gemm_qkv(
    const u16* __restrict__ xb,
    const u16* __restrict__ wq, const u16* __restrict__ wk, const u16* __restrict__ wv,
    u16* __restrict__ Qb, u16* __restrict__ Kb, u16* __restrict__ Vtb,
    const int* __restrict__ pos)
{
    __shared__ u16 LS[16384];   // single 32KB allocation for all instantiations
    const int z = blockIdx.z;
    if      (z == 0) gemm_body<1>(LS, xb, wq, Qb,  nullptr, pos, blockIdx.y*128, blockIdx.x*128);
    else if (z == 1) gemm_body<2>(LS, xb, wk, Kb,  nullptr, pos, blockIdx.y*128, blockIdx.x*128);
    else             gemm_body<3>(LS, xb, wv, Vtb, nullptr, pos, blockIdx.y*128, blockIdx.x*128);
}

__global__ __launch_bounds__(256) void k_gemm_o(
    const u16* __restrict__ yb, const u16* __restrict__ wo, float* __restrict__ out)
{
    __shared__ u16 LS[16384];
    gemm_body<0>(LS, yb, wo, nullptr, out, nullptr, blockIdx.y*128, blockIdx.x*128);
}

// ---------------------------------------------------------------------------
// Causal flash attention, QBLK=64 (1024 blocks, 4/CU), in-register P,
// zero ds_writes, DEFERRED-PV pipeline (T15), deferred l-sum:
// per-lane partial l-sums (sf rescale is row-uniform so partials scale
// correctly), reduced ONCE in the epilogue. Cross-lane max via __shfl_xor
// (round-11-proven; permlane-swap inline asm had a register-aliasing bug).
//   St = mfma(A=K-rows, B=Q-rows) -> lane holds P[k=l4*4+r][q=l15]
//   = B-frag of mfma_16x16x16bf16_1k. PV: O^T = mfma(A=V^T-frag, B=P).
// K and V^T staged via global_load_lds DMA (XOR-involution source map).
// ---------------------------------------------------------------------------
__global__ __launch_bounds__(256, 4) void k_attn(
    const u16* __restrict__ Qb, const u16* __restrict__ Kb,
    const u16* __restrict__ Vtb, u16* __restrict__ Yb)
{
    __shared__ u16 Kls[2][4096];   // [buf] rows=key,  cols=d (swizzled)
    __shared__ u16 Vls[2][4096];   // [buf] rows=d, cols=perm(k) (swizzled)
    const int tid  = threadIdx.x;
    const int lane = tid & 63, wv = tid >> 6;
    const int l15  = lane & 15, l4 = lane >> 4;
    const int bh   = blockIdx.x;             // b*16+h
    const int qt   = 31 - blockIdx.y;        // longest blocks dispatch first
    const int qw   = qt * 64 + wv * 16;      // wave's first query
    const size_t base = (size_t)bh * SEQ * HDIM;
    const u16* Qg = Qb  + base;
    const u16* Kg = Kb  + base;
    const u16* Vg = Vtb + base;              // [d][s] layout

    const int sw  = (l15 & 7) << 4;
    const int rb0 = l15 * 128 + ((l4 * 16) ^ sw);
    const int rb1 = l15 * 128 + ((64 + l4 * 16) ^ sw);

    // Q B-frags (RoPE + scale already applied): B[n=q=l15][kk=d=l4*8+i]
    bf16x8 qf[2];
#pragma unroll
    for (int ks = 0; ks < 2; ks++)
        qf[ks] = as_bf(*(const ushort8*)(
            Qg + (size_t)(qw + l15) * HDIM + ks * 32 + l4 * 8));

    const f32x4 zz = {0.f, 0.f, 0.f, 0.f};
    f32x4 acc[4];                 // O^T: lane holds [d=nd*16+l4*4+r][q=l15]
    float mst = -1e30f, lstp = 0.f;   // lstp: per-lane PARTIAL l-sum
#pragma unroll
    for (int n = 0; n < 4; n++) acc[n] = zz;

    // deferred-PV state: P(prev) and V-frags(prev) in registers (zero-init
    // so the first PV adds exact zeros)
    const s16x4 zs = {0, 0, 0, 0};
    const s16x8 zs8 = {0, 0, 0, 0, 0, 0, 0, 0};
    s16x4 pbp[4] = {zs, zs, zs, zs};
    s16x8 vwp[2][4];
#pragma unroll
    for (int a = 0; a < 2; a++)
#pragma unroll
        for (int b = 0; b < 4; b++) vwp[a][b] = zs8;

    // DMA source offsets (u16 elems; involution matches rb0/rb1 reads)
    const int sK0 = tid, sK1 = 256 + tid;
    const int c0 = (sK0 & 7) ^ ((sK0 >> 3) & 7), c1 = (sK1 & 7) ^ ((sK1 >> 3) & 7);
    const int gK0 = ((sK0 >> 3) << 6) + (c0 << 3);           // K: row stride 64
    const int gK1 = ((sK1 >> 3) << 6) + (c1 << 3);
    const int gV0 = (sK0 >> 3) * SEQ + (c0 << 3);            // V^T: row stride 2048
    const int gV1 = (sK1 >> 3) * SEQ + (c1 << 3);

    const int nkb = qt + 1;

    dma16(Kg + gK0, &Kls[0][0] + wv * 512);
    dma16(Kg + gK1, &Kls[0][0] + 2048 + wv * 512);
    dma16(Vg + gV0, &Vls[0][0] + wv * 512);
    dma16(Vg + gV1, &Vls[0][0] + 2048 + wv * 512);
    __syncthreads();

    for (int kb = 0; kb < nkb; ++kb) {
        const int cur = kb & 1;
        if (kb + 1 < nkb) {
            const size_t roK = (size_t)(kb + 1) * 64 * HDIM;
            const int    roV = (kb + 1) * 64;
            u16* kd = &Kls[cur ^ 1][0];
            u16* vd = &Vls[cur ^ 1][0];
            dma16(Kg + roK + gK0, kd + wv * 512);
            dma16(Kg + roK + gK1, kd + 2048 + wv * 512);
            dma16(Vg + roV + gV0, vd + wv * 512);
            dma16(Vg + roV + gV1, vd + 2048 + wv * 512);
        }

        // --- K A-frag reads first (latency hides under PV(prev) MFMAs) ---
        const char* Kbase = (const char*)&Kls[cur][0];
        const char* Vbase = (const char*)&Vls[cur][0];
        bf16x8 kf[4][2];
#pragma unroll
        for (int nt = 0; nt < 4; nt++) {
            kf[nt][0] = as_bf(*(const ushort8*)(Kbase + nt * 2048 + rb0));
            kf[nt][1] = as_bf(*(const ushort8*)(Kbase + nt * 2048 + rb1));
        }

        __builtin_amdgcn_s_setprio(1);
        // --- PV(prev): register-only, no dependencies -> fills MFMA pipe ---
#pragma unroll
        for (int nt2 = 0; nt2 < 2; nt2++)
#pragma unroll
            for (int nd = 0; nd < 4; nd++) {
                const s16x4 vlo = __builtin_shufflevector(vwp[nt2][nd], vwp[nt2][nd],
                                                          0, 1, 2, 3);
                const s16x4 vhi = __builtin_shufflevector(vwp[nt2][nd], vwp[nt2][nd],
                                                          4, 5, 6, 7);
                acc[nd] = __builtin_amdgcn_mfma_f32_16x16x16bf16_1k(
                    vlo, pbp[2 * nt2], acc[nd], 0, 0, 0);
                acc[nd] = __builtin_amdgcn_mfma_f32_16x16x16bf16_1k(
                    vhi, pbp[2 * nt2 + 1], acc[nd], 0, 0, 0);
            }
        // --- S^T = K·Q^T : lane holds S[k=kb*64+nt*16+l4*4+r][q=qw+l15] ---
        f32x4 st[4];
#pragma unroll
        for (int nt = 0; nt < 4; nt++) {
            f32x4 sv = mfma16(kf[nt][0], qf[0], zz);
            st[nt]   = mfma16(kf[nt][1], qf[1], sv);
        }
        __builtin_amdgcn_s_setprio(0);

        // --- V frags for THIS tile -> regs (consumed next step / epilogue) ---
#pragma unroll
        for (int nt2 = 0; nt2 < 2; nt2++) {
            const int rb = nt2 ? rb1 : rb0;
#pragma unroll
            for (int nd = 0; nd < 4; nd++)
                vwp[nt2][nd] = *(const s16x8*)(Vbase + nd * 2048 + rb);
        }

        if (kb == qt) {               // diagonal tile: causal mask
            const int qg = qw + l15;
            const int kbb = kb * 64;
#pragma unroll
            for (int nt = 0; nt < 4; nt++)
#pragma unroll
                for (int r = 0; r < 4; r++) {
                    const int kg = kbb + nt * 16 + l4 * 4 + r;
                    st[nt][r] = (kg <= qg) ? st[nt][r] : -1e30f;
                }
        }

        // --- online softmax (overlaps PV(prev) MFMAs on the VALU pipe) ---
        float m0 = fmaxf(fmaxf(st[0][0], st[0][1]), fmaxf(st[0][2], st[0][3]));
        float m1 = fmaxf(fmaxf(st[1][0], st[1][1]), fmaxf(st[1][2], st[1][3]));
        float m2 = fmaxf(fmaxf(st[2][0], st[2][1]), fmaxf(st[2][2], st[2][3]));
        float m3 = fmaxf(fmaxf(st[3][0], st[3][1]), fmaxf(st[3][2], st[3][3]));
        float m  = fmaxf(fmaxf(m0, m1), fmaxf(m2, m3));
        m = fmaxf(m, __shfl_xor(m, 16));
        m = fmaxf(m, __shfl_xor(m, 32));
        if (!__all(m - mst <= 8.0f)) {        // defer-max (T13, base-2 units)
            const float mn = fmaxf(mst, m);   // (acc read waits on PV MFMAs
            const float sf = exp2f(mst - mn); //  via register dependency)
            mst = mn;
            lstp *= sf;                       // partial scales uniformly
#pragma unroll
            for (int nd = 0; nd < 4; nd++) acc[nd] *= sf;
        }
        const float mm = mst;
        float pg[4];
#pragma unroll
        for (int nt = 0; nt < 4; nt++) {
            float p0 = exp2f(st[nt][0] - mm), p1 = exp2f(st[nt][1] - mm);
            float p2 = exp2f(st[nt][2] - mm), p3 = exp2f(st[nt][3] - mm);
            pg[nt] = (p0 + p1) + (p2 + p3);
            s16x4 pv;
            pv[0] = (short)__builtin_bit_cast(u16, (__bf16)p0);
            pv[1] = (short)__builtin_bit_cast(u16, (__bf16)p1);
            pv[2] = (short)__builtin_bit_cast(u16, (__bf16)p2);
            pv[3] = (short)__builtin_bit_cast(u16, (__bf16)p3);
            pbp[nt] = pv;                     // P for NEXT step's PV
        }
        lstp += (pg[0] + pg[1]) + (pg[2] + pg[3]);   // per-lane partial only

        __syncthreads();   // drains DMA + V reads -> next buffers ready
    }

    // --- drain PV(last) ---
    __builtin_amdgcn_s_setprio(1);
#pragma unroll
    for (int nt2 = 0; nt2 < 2; nt2++)
#pragma unroll
        for (int nd = 0; nd < 4; nd++) {
            const s16x4 vlo = __builtin_shufflevector(vwp[nt2][nd], vwp[nt2][nd],
                                                      0, 1, 2, 3);
            const s16x4 vhi = __builtin_shufflevector(vwp[nt2][nd], vwp[nt2][nd],
                                                      4, 5, 6, 7);
            acc[nd] = __builtin_amdgcn_mfma_f32_16x16x16bf16_1k(
                vlo, pbp[2 * nt2], acc[nd], 0, 0, 0);
            acc[nd] = __builtin_amdgcn_mfma_f32_16x16x16bf16_1k(
                vhi, pbp[2 * nt2 + 1], acc[nd], 0, 0, 0);
        }
    __builtin_amdgcn_s_setprio(0);

    // --- cross-lane l-sum reduce ONCE; write /lst ---
    float lst = lstp;
    lst += __shfl_xor(lst, 16);
    lst += __shfl_xor(lst, 32);
    const int b = bh >> 4, h = bh & 15;
    const float inv = 1.0f / lst;
    const int q = qw + l15;
#pragma unroll
    for (int nd = 0; nd < 4; nd++) {
        u16x4 o;
#pragma unroll
        for (int r = 0; r < 4; r++)
            o[r] = __builtin_bit_cast(u16, (__bf16)(acc[nd][r] * inv));
        const int d = nd * 16 + l4 * 4;
        *(u16x4*)(Yb + (size_t)(b * SEQ + q) * D_MODEL + h * HDIM + d) = o;
    }
}

// ---------------------------------------------------------------------------
extern "C" void kernel_launch(void* const* d_in, const int* in_sizes, int n_in,
                              void* d_out, int out_size, void* d_ws, size_t ws_size,
                              hipStream_t stream)
{
    const float* x  = (const float*)d_in[0];
    const float* wq = (const float*)d_in[1];
    const float* wk = (const float*)d_in[2];
    const float* wv = (const float*)d_in[3];
    const float* wo = (const float*)d_in[4];
    const int*  pos = (const int*)d_in[5];
    float* out = (float*)d_out;

    // workspace (bf16): [x 4M | wq 1M | wk 1M | wv 1M | wo 1M | Q 4M | K 4M | Vt 4M]
    // y (attention output) aliases x (x is dead after the QKV GEMM).
    if (ws_size < (size_t)41943040) return;
    u16* xb  = (u16*)d_ws;
    u16* wqb = xb  + (size_t)4 * SEG;
    u16* wkb = wqb + SEG;
    u16* wvb = wkb + SEG;
    u16* wob = wvb + SEG;
    u16* Qb  = wob + SEG;
    u16* Kb  = Qb  + (size_t)4 * SEG;
    u16* Vtb = Kb  + (size_t)4 * SEG;   // [b,h,d,s], k-permuted per 64-block
    u16* Yb  = xb;

    k_cvt     <<<dim3(512, 1, 8), 256, 0, stream>>>(x, wq, wk, wv, wo, xb);
    k_gemm_qkv<<<dim3(8, 32, 3),  256, 0, stream>>>(xb, wqb, wkb, wvb, Qb, Kb, Vtb, pos);
    k_attn    <<<dim3(32, 32),    256, 0, stream>>>(Qb, Kb, Vtb, Yb);
    k_gemm_o  <<<dim3(8, 32),     256, 0, stream>>>(Yb, wob, out);
}